// Round 1
// baseline (317.592 us; speedup 1.0000x reference)
//
#include <hip/hip_runtime.h>

// 3-level db4 band-split, one block per row, T=1024, all intermediates in LDS.
// R1: full-occupancy (2 blocks/CU x 16 waves), paired outputs, merged phases.
// R2: (a) tail-phase merge — a3 and d3 reconstruction chains run side-by-side,
//     8 phases -> 6, 7 barriers -> 5; (b) fwd_interior reads 3x float4 instead
//     of 5x float2 (conflict-free: 32/32 banks vs 16/32, fewer instructions).

#define T     1024
#define N0    8192
#define L1    4099
#define L2    2053
#define L3    1030
#define NROWS 2048

#define RL0 0.23037781330885523f
#define RL1 0.7148465705525415f
#define RL2 0.6308807679295904f
#define RL3 (-0.02798376941698385f)
#define RL4 (-0.18703481171888114f)
#define RL5 0.030841381835986965f
#define RL6 0.032883011666982945f
#define RL7 (-0.010597401784997278f)

// ---- forward DWT: interior pairs (no clamps). Outputs i0=2t, i0+1 for
// t in [2, tHi). Window w = s[4t-6 .. 4t+3] covered by float4 q0,q1,q2 =
// floats [4t-8 .. 4t+3] (16B-aligned since 4t-8 = 4*(t-2)).
__device__ __forceinline__ void fwd_interior(const float* __restrict__ s, int tHi,
                                             float* __restrict__ dstA,
                                             float* __restrict__ dstD, int tid)
{
    const float lo[8] = {RL0, RL1, RL2, RL3, RL4, RL5, RL6, RL7};
    const float hi[8] = {RL7, -RL6, RL5, -RL4, RL3, -RL2, RL1, -RL0};
    const float4* s4 = (const float4*)s;
    for (int t = 2 + tid; t < tHi; t += T) {
        float4 q0 = s4[t - 2], q1 = s4[t - 1], q2 = s4[t];
        float w[10] = {q0.z, q0.w, q1.x, q1.y, q1.z, q1.w,
                       q2.x, q2.y, q2.z, q2.w};
        float sa0 = 0.f, sd0 = 0.f, sa1 = 0.f, sd1 = 0.f;
#pragma unroll
        for (int k = 0; k < 8; ++k) {
            sa0 = fmaf(w[k],     lo[k], sa0);
            sd0 = fmaf(w[k],     hi[k], sd0);
            sa1 = fmaf(w[k + 2], lo[k], sa1);
            sd1 = fmaf(w[k + 2], hi[k], sd1);
        }
        ((float2*)dstA)[t] = make_float2(sa0, sa1);
        ((float2*)dstD)[t] = make_float2(sd0, sd1);
    }
}

// ---- forward DWT: edge outputs with symmetric clamp (i<4 or i>=2*tHi).
__device__ __forceinline__ void fwd_edges(const float* __restrict__ s, int n, int Lout, int tHi,
                                          float* __restrict__ dstA,
                                          float* __restrict__ dstD, int tid)
{
    const float lo[8] = {RL0, RL1, RL2, RL3, RL4, RL5, RL6, RL7};
    const float hi[8] = {RL7, -RL6, RL5, -RL4, RL3, -RL2, RL1, -RL0};
    const int ub = 2 * tHi;
    const int tot = 4 + (Lout - ub);
    if (tid < tot) {
        int i = (tid < 4) ? tid : ub + (tid - 4);
        int j0 = 2 * i - 6;
        float sa = 0.f, sd = 0.f;
#pragma unroll
        for (int t = 0; t < 8; ++t) {
            int m = j0 + t;
            m = (m < 0) ? (-1 - m) : m;
            m = (m >= n) ? (2 * n - 1 - m) : m;
            float v = s[m];
            sa = fmaf(v, lo[t], sa);
            sd = fmaf(v, hi[t], sd);
        }
        dstA[i] = sa;
        dstD[i] = sd;
    }
}

// ---- upsample-conv, LDS->LDS. 4 outputs per iter (p=2t,2t+1), float4 store.
__device__ __forceinline__ void upconv_mid(const float* __restrict__ s, float* __restrict__ dst,
                                           int L,
                                           float o0, float o1, float o2, float o3,
                                           float e0, float e1, float e2, float e3, int tid)
{
    const float2* s2 = (const float2*)s;
    const int cnt = L - 3, P2 = cnt >> 1;
    for (int t = tid; t < P2; t += T) {
        float2 u0 = s2[t], u1 = s2[t + 1];
        float s4 = s[2 * t + 4];
        float a0 = u0.x, a1 = u0.y, a2 = u1.x, a3 = u1.y;
        float ev0 = a0 * e0 + a1 * e1 + a2 * e2 + a3 * e3;
        float od0 = a0 * o0 + a1 * o1 + a2 * o2 + a3 * o3;
        float ev1 = a1 * e0 + a2 * e1 + a3 * e2 + s4 * e3;
        float od1 = a1 * o0 + a2 * o1 + a3 * o2 + s4 * o3;
        ((float4*)dst)[t] = make_float4(ev0, od0, ev1, od1);
    }
    if ((cnt & 1) && tid == 0) {           // tail p = L-4 (odd) when cnt odd
        int p = cnt - 1;
        float s0 = s[p], s1 = s[p + 1], sc = s[p + 2], s3 = s[p + 3];
        float ev = s0 * e0 + s1 * e1 + sc * e2 + s3 * e3;
        float od = s0 * o0 + s1 * o1 + sc * o2 + s3 * o3;
        *(float2*)&dst[2 * p] = make_float2(ev, od);
    }
}

// ---- final upsample-conv (L=4099 -> 8192), float4 stores to global.
__device__ __forceinline__ void upconv_final(const float* __restrict__ s, float* __restrict__ g,
                                             float o0, float o1, float o2, float o3,
                                             float e0, float e1, float e2, float e3, int tid)
{
    const float2* s2 = (const float2*)s;
    for (int q = tid; q < N0 / 4; q += T) {
        float2 u0 = s2[q], u1 = s2[q + 1];
        float s4 = s[2 * q + 4];
        float a0 = u0.x, a1 = u0.y, a2 = u1.x, a3 = u1.y;
        float4 o;
        o.x = a0 * e0 + a1 * e1 + a2 * e2 + a3 * e3;
        o.y = a0 * o0 + a1 * o1 + a2 * o2 + a3 * o3;
        o.z = a1 * e0 + a2 * e1 + a3 * e2 + s4 * e3;
        o.w = a1 * o0 + a2 * o1 + a3 * o2 + s4 * o3;
        ((float4*)g)[q] = o;
    }
}

// LDS pool (floats), all offsets multiple of 4 for float4 alignment.
// Aliased lifetimes:
//   [0,4112):      a1 (A,B) -> t2 (C,D)  -> u2 (E,F)
//   [4112,8224):   d1 (A,B) -> u1 [4112,6166) + v1 [6168,8222)  (D,E)
//   [8224,12336):  a2 [8224,10277) + d2 [10280,12333) (B,C) -> v2 (E,F)
//   [12336,14400): a3 [12336,13366) + d3 [13368,14398) (C,D)
#define POOL_F 14400

__global__ __launch_bounds__(T) void wavelet_bands(const float* __restrict__ x,
                                                   float* __restrict__ out)
{
    __shared__ float buf[POOL_F];
    const int tid = threadIdx.x;
    const int row = blockIdx.x;

    float* a1 = buf;
    float* t2 = buf;
    float* u2 = buf;
    float* d1 = buf + 4112;
    float* u1 = buf + 4112;
    float* v1 = buf + 6168;
    float* a2 = buf + 8224;
    float* v2 = buf + 8224;
    float* d2 = buf + 10280;
    float* a3 = buf + 12336;
    float* d3 = buf + 13368;

    const float* xr = x + (size_t)row * N0;
    const size_t band = (size_t)NROWS * N0;
    float* o0 = out + (size_t)row * N0;  // a3 band
    float* o1 = o0 + band;               // d3
    float* o2 = o0 + 2 * band;           // d2
    float* o3 = o0 + 3 * band;           // d1

    // tap sets:  up_LO: odd {RL7,RL5,RL3,RL1}, even {RL6,RL4,RL2,RL0}
    //            up_HI: odd {-RL0,-RL2,-RL4,-RL6}, even {RL1,RL3,RL5,RL7}
    const int tHi1 = (N0 - 3) >> 2;   // 2047
    const int tHi2 = (L1 - 3) >> 2;   // 1024
    const int tHi3 = (L2 - 3) >> 2;   // 512

    // Phase A: level-1 forward from global
    fwd_interior(xr, tHi1, a1, d1, tid);
    fwd_edges(xr, N0, L1, tHi1, a1, d1, tid);
    __syncthreads();

    // Phase B: band d1 -> o3  ||  level-2 forward (a1 -> a2,d2)
    upconv_final(d1, o3, -RL0, -RL2, -RL4, -RL6, RL1, RL3, RL5, RL7, tid);
    fwd_interior(a1, tHi2, a2, d2, tid);
    fwd_edges(a1, L1, L2, tHi2, a2, d2, tid);
    __syncthreads();

    // Phase C: level-3 forward (a2 -> a3,d3)  ||  d2 stage1: up_HI(d2) -> t2
    fwd_interior(a2, tHi3, a3, d3, tid);
    fwd_edges(a2, L2, L3, tHi3, a3, d3, tid);
    upconv_mid(d2, t2, L2, -RL0, -RL2, -RL4, -RL6, RL1, RL3, RL5, RL7, tid);
    __syncthreads();

    // Phase D: band d2 -> o2  ||  up_LO(a3) -> u1  ||  up_HI(d3) -> v1
    upconv_final(t2, o2, RL7, RL5, RL3, RL1, RL6, RL4, RL2, RL0, tid);
    upconv_mid(a3, u1, L3, RL7, RL5, RL3, RL1, RL6, RL4, RL2, RL0, tid);
    upconv_mid(d3, v1, L3, -RL0, -RL2, -RL4, -RL6, RL1, RL3, RL5, RL7, tid);
    __syncthreads();

    // Phase E: up_LO(u1) -> u2  ||  up_LO(v1) -> v2
    upconv_mid(u1, u2, L2, RL7, RL5, RL3, RL1, RL6, RL4, RL2, RL0, tid);
    upconv_mid(v1, v2, L2, RL7, RL5, RL3, RL1, RL6, RL4, RL2, RL0, tid);
    __syncthreads();

    // Phase F: band a3 -> o0  ||  band d3 -> o1
    upconv_final(u2, o0, RL7, RL5, RL3, RL1, RL6, RL4, RL2, RL0, tid);
    upconv_final(v2, o1, RL7, RL5, RL3, RL1, RL6, RL4, RL2, RL0, tid);
}

extern "C" void kernel_launch(void* const* d_in, const int* in_sizes, int n_in,
                              void* d_out, int out_size, void* d_ws, size_t ws_size,
                              hipStream_t stream)
{
    const float* x = (const float*)d_in[0];
    float* out = (float*)d_out;
    wavelet_bands<<<NROWS, T, 0, stream>>>(x, out);
}